// Round 4
// baseline (21.572 us; speedup 1.0000x reference)
//
#include <hip/hip_runtime.h>

#define LOG2F_ 0.69314718056f

__device__ __forceinline__ float softplus_f(float x) {
    return fmaxf(x, 0.f) + log1pf(expf(-fabsf(x)));
}

// Single fused kernel; every block contributes independently to d_out.
//  blocks [0,288):   obj blocks, blk = sb*3 + a. Contribution = 50*nv_sb*objpart/32.
//  blocks [288,768): target blocks, 1 wave per (sb,t). Contribution = per-target loss/32.
__global__ void yolo_fused_kernel(const float* __restrict__ p0,
                                  const float* __restrict__ p1,
                                  const float* __restrict__ p2,
                                  const float* __restrict__ targets,
                                  const float* __restrict__ anchors,
                                  float* __restrict__ out) {
    int blk  = blockIdx.x;
    int wave = threadIdx.x >> 6;
    int lane = threadIdx.x & 63;
    __shared__ float partl[4];

    if (blk < 288) {
        // ---- obj block: sb = blk/3, anchor a = blk%3 ----
        int sb = blk / 3;
        int a  = blk - sb * 3;
        int s  = sb >> 5, b = sb & 31;
        const float* p; int G; float inv_stride;
        if (s == 0)      { p = p0; G = 13; inv_stride = 1.f / 32.f; }
        else if (s == 1) { p = p1; G = 26; inv_stride = 1.f / 16.f; }
        else             { p = p2; G = 52; inv_stride = 1.f / 8.f;  }
        int GG = G * G;
        const float* src = p + ((size_t)(b * 255 + a * 85 + 4)) * GG;
        float sum = 0.f;
        for (int i = threadIdx.x; i < GG; i += 256)
            sum += softplus_f(src[i]);
        for (int off = 32; off > 0; off >>= 1) sum += __shfl_down(sum, off);
        if (lane == 0) partl[wave] = sum;

        // nv_sb: lanes 0..19 of wave 0 test validity of target t=lane.
        float nv = 0.f;
        if (wave == 0) {
            bool valid = false;
            if (lane < 20) {
                const float* tg = targets + (b * 20 + lane) * 5;
                float gx = tg[1] * inv_stride, gy = tg[2] * inv_stride;
                float fgi = floorf(gx), fgj = floorf(gy);
                valid = (fgi >= 0.f) && (fgi < (float)G) &&
                        (fgj >= 0.f) && (fgj < (float)G);
            }
            unsigned long long m = __ballot(valid);
            nv = (float)__popcll(m);
        }
        __syncthreads();
        if (threadIdx.x == 0) {
            float objpart = partl[0] + partl[1] + partl[2] + partl[3];
            atomicAdd(out, (50.f / 32.f) * nv * objpart);
        }
    } else {
        // ---- target block: 4 waves, one (sb,t) each ----
        int tb = blk - 288;
        int gw = tb * 4 + wave;            // 0..1919
        int sb = gw / 20;
        int t  = gw - sb * 20;
        int s  = sb >> 5, b = sb & 31;

        const float* p; int G; float inv_stride;
        if (s == 0)      { p = p0; G = 13; inv_stride = 1.f / 32.f; }
        else if (s == 1) { p = p1; G = 26; inv_stride = 1.f / 16.f; }
        else             { p = p2; G = 52; inv_stride = 1.f / 8.f;  }
        int GG = G * G;

        const float* tg = targets + (b * 20 + t) * 5;
        float tc_f = tg[0];
        float x1 = tg[1], y1 = tg[2], x2 = tg[3], y2 = tg[4];
        float gx = x1 * inv_stride, gy = y1 * inv_stride;
        float gw_ = (x2 - x1) * inv_stride, gh_ = (y2 - y1) * inv_stride;
        float fgi = floorf(gx), fgj = floorf(gy);
        bool valid = (fgi >= 0.f) && (fgi < (float)G) && (fgj >= 0.f) && (fgj < (float)G);
        float vm = valid ? 1.f : 0.f;
        int gi = (int)fminf(fmaxf(fgi, 0.f), (float)(G - 1));
        int gj = (int)fminf(fmaxf(fgj, 0.f), (float)(G - 1));

        // best anchor, first-max (strict >) semantics
        float best_iou = -1.f, best_aw = 0.f, best_ah = 0.f; int best = 0;
        for (int a = 0; a < 3; ++a) {
            float aw = anchors[(s * 3 + a) * 2 + 0] * inv_stride;
            float ah = anchors[(s * 3 + a) * 2 + 1] * inv_stride;
            float inter = fminf(gw_, aw) * fminf(gh_, ah);
            float uni   = gw_ * gh_ + aw * ah - inter;
            float iou   = inter / (uni + 1e-16f);
            if (iou > best_iou) { best_iou = iou; best = a; best_aw = aw; best_ah = ah; }
        }

        float gtx = gx - (float)gi, gty = gy - (float)gj;
        float gtw = logf(fmaxf(gw_, 1e-16f) / (best_aw + 1e-16f));
        float gth = logf(fmaxf(gh_, 1e-16f) / (best_ah + 1e-16f));
        int   tc  = (int)tc_f;

        const float* base = p + ((size_t)(b * 255 + best * 85)) * GG + gj * G + gi;

        float v0 = base[(size_t)lane * GG];
        float v1 = (lane < 21) ? base[(size_t)(64 + lane) * GG] : 0.f;

        float term;
        int c = lane;
        if (c == 0) {
            float px = 1.f / (1.f + expf(-v0));
            term = 5.f * (px - gtx) * (px - gtx);
        } else if (c == 1) {
            float py = 1.f / (1.f + expf(-v0));
            term = 5.f * (py - gty) * (py - gty);
        } else if (c == 2) {
            term = 5.f * (v0 - gtw) * (v0 - gtw);
        } else if (c == 3) {
            term = 5.f * (v0 - gth) * (v0 - gth);
        } else if (c == 4) {
            term = softplus_f(-v0) - 50.f * softplus_f(v0);
        } else {
            term = softplus_f(v0) - ((c - 5 == tc) ? v0 : 0.f);
        }
        if (lane < 21) {
            int c1 = 64 + lane;
            term += softplus_f(v1) - ((c1 - 5 == tc) ? v1 : 0.f);
        }

        for (int off = 32; off > 0; off >>= 1) term += __shfl_down(term, off);

        if (lane == 0)
            partl[wave] = vm * (term + 50.f * LOG2F_);
        __syncthreads();
        if (threadIdx.x == 0)
            atomicAdd(out, (partl[0] + partl[1] + partl[2] + partl[3]) * (1.f / 32.f));
    }
}

extern "C" void kernel_launch(void* const* d_in, const int* in_sizes, int n_in,
                              void* d_out, int out_size, void* d_ws, size_t ws_size,
                              hipStream_t stream) {
    const float* p0      = (const float*)d_in[0];
    const float* p1      = (const float*)d_in[1];
    const float* p2      = (const float*)d_in[2];
    const float* targets = (const float*)d_in[3];
    const float* anchors = (const float*)d_in[4];
    float* out = (float*)d_out;

    hipMemsetAsync(out, 0, sizeof(float), stream);
    yolo_fused_kernel<<<768, 256, 0, stream>>>(p0, p1, p2, targets, anchors, out);
}

// Round 5
// 15.654 us; speedup vs baseline: 1.3780x; 1.3780x over previous
//
#include <hip/hip_runtime.h>

#define LOG2F_ 0.69314718056f
#define N_TGT_WAVES 1920   // 96 (s,b) x 20 targets
#define N_OBJ_UNITS 576    // s0:96x169, s1:96x676, s2:384x676-chunks
#define N_BLOCKS 624       // (1920+576)/4
#define N_SLOTS 624

__device__ __forceinline__ float softplus_f(float x) {
    return fmaxf(x, 0.f) + log1pf(expf(-fabsf(x)));
}

// 624 blocks x 4 waves; every wave is an independent work item.
//  waves [0,1920): one target (sb,t) each — gather 85 channels, loss terms.
//  waves [1920,2496): one obj chunk (s,b,a,chunk) — softplus-sum * 50*nv_sb/32.
// Block combines its 4 wave partials into slots[blk]. No atomics, no init.
__global__ __launch_bounds__(256)
void yolo_main(const float* __restrict__ p0,
               const float* __restrict__ p1,
               const float* __restrict__ p2,
               const float* __restrict__ targets,
               const float* __restrict__ anchors,
               float* __restrict__ slots) {
    int wave = threadIdx.x >> 6;
    int lane = threadIdx.x & 63;
    int w    = blockIdx.x * 4 + wave;
    float contrib = 0.f;   // meaningful on lane 0 after reduce

    if (w < N_TGT_WAVES) {
        // ---------------- target wave ----------------
        int sb = w / 20;
        int t  = w - sb * 20;
        int s  = sb >> 5, b = sb & 31;

        const float* p; int G; float inv_stride;
        if (s == 0)      { p = p0; G = 13; inv_stride = 1.f / 32.f; }
        else if (s == 1) { p = p1; G = 26; inv_stride = 1.f / 16.f; }
        else             { p = p2; G = 52; inv_stride = 1.f / 8.f;  }
        int GG = G * G;

        const float* tg = targets + (b * 20 + t) * 5;
        float tc_f = tg[0];
        float x1 = tg[1], y1 = tg[2], x2 = tg[3], y2 = tg[4];
        float gx = x1 * inv_stride, gy = y1 * inv_stride;
        float gw_ = (x2 - x1) * inv_stride, gh_ = (y2 - y1) * inv_stride;
        float fgi = floorf(gx), fgj = floorf(gy);
        bool valid = (fgi >= 0.f) && (fgi < (float)G) && (fgj >= 0.f) && (fgj < (float)G);
        float vm = valid ? 1.f : 0.f;
        int gi = (int)fminf(fmaxf(fgi, 0.f), (float)(G - 1));
        int gj = (int)fminf(fmaxf(fgj, 0.f), (float)(G - 1));

        // best anchor, first-max (strict >) semantics
        float best_iou = -1.f, best_aw = 0.f, best_ah = 0.f;
        for (int a = 0; a < 3; ++a) {
            float aw = anchors[(s * 3 + a) * 2 + 0] * inv_stride;
            float ah = anchors[(s * 3 + a) * 2 + 1] * inv_stride;
            float inter = fminf(gw_, aw) * fminf(gh_, ah);
            float uni   = gw_ * gh_ + aw * ah - inter;
            float iou   = inter / (uni + 1e-16f);
            if (iou > best_iou) { best_iou = iou; best_aw = aw; best_ah = ah; }
        }
        // recover index implicitly via aw/ah; need channel index: recompute
        int best = 0; best_iou = -1.f;
        for (int a = 0; a < 3; ++a) {
            float aw = anchors[(s * 3 + a) * 2 + 0] * inv_stride;
            float ah = anchors[(s * 3 + a) * 2 + 1] * inv_stride;
            float inter = fminf(gw_, aw) * fminf(gh_, ah);
            float uni   = gw_ * gh_ + aw * ah - inter;
            float iou   = inter / (uni + 1e-16f);
            if (iou > best_iou) { best_iou = iou; best = a; }
        }

        float gtx = gx - (float)gi, gty = gy - (float)gj;
        float gtw = logf(fmaxf(gw_, 1e-16f) / (best_aw + 1e-16f));
        float gth = logf(fmaxf(gh_, 1e-16f) / (best_ah + 1e-16f));
        int   tc  = (int)tc_f;

        const float* base = p + ((size_t)(b * 255 + best * 85)) * GG + gj * G + gi;
        float v0 = base[(size_t)lane * GG];
        float v1 = (lane < 21) ? base[(size_t)(64 + lane) * GG] : 0.f;

        float term;
        int c = lane;
        if (c == 0) {
            float px = 1.f / (1.f + expf(-v0));
            term = 5.f * (px - gtx) * (px - gtx);
        } else if (c == 1) {
            float py = 1.f / (1.f + expf(-v0));
            term = 5.f * (py - gty) * (py - gty);
        } else if (c == 2) {
            term = 5.f * (v0 - gtw) * (v0 - gtw);
        } else if (c == 3) {
            term = 5.f * (v0 - gth) * (v0 - gth);
        } else if (c == 4) {
            term = softplus_f(-v0) - 50.f * softplus_f(v0);
        } else {
            term = softplus_f(v0) - ((c - 5 == tc) ? v0 : 0.f);
        }
        if (lane < 21) {
            int c1 = 64 + lane;
            term += softplus_f(v1) - ((c1 - 5 == tc) ? v1 : 0.f);
        }

        for (int off = 32; off > 0; off >>= 1) term += __shfl_down(term, off);
        if (lane == 0) contrib = vm * (term + 50.f * LOG2F_) * (1.f / 32.f);
    } else {
        // ---------------- obj chunk wave ----------------
        int u = w - N_TGT_WAVES;   // 0..575
        int s, b, a, off, len;
        if (u < 96)       { s = 0; b = u / 3;  a = u % 3;  off = 0; len = 169; }
        else if (u < 192) { int v = u - 96;  s = 1; b = v / 3; a = v % 3; off = 0; len = 676; }
        else              { int v = u - 192; s = 2; b = v / 12; int r = v % 12;
                            a = r >> 2; off = (r & 3) * 676; len = 676; }

        const float* p; int G; float inv_stride;
        if (s == 0)      { p = p0; G = 13; inv_stride = 1.f / 32.f; }
        else if (s == 1) { p = p1; G = 26; inv_stride = 1.f / 16.f; }
        else             { p = p2; G = 52; inv_stride = 1.f / 8.f;  }
        int GG = G * G;

        const float* src = p + ((size_t)(b * 255 + a * 85 + 4)) * GG + off;
        float sum = 0.f;
        for (int i = lane; i < len; i += 64)
            sum += softplus_f(src[i]);
        for (int o = 32; o > 0; o >>= 1) sum += __shfl_down(sum, o);

        // nv_sb: lanes 0..19 test target validity at this scale
        bool valid = false;
        if (lane < 20) {
            const float* tg = targets + (b * 20 + lane) * 5;
            float gx = tg[1] * inv_stride, gy = tg[2] * inv_stride;
            float fgi = floorf(gx), fgj = floorf(gy);
            valid = (fgi >= 0.f) && (fgi < (float)G) &&
                    (fgj >= 0.f) && (fgj < (float)G);
        }
        float nv = (float)__popcll(__ballot(valid));
        if (lane == 0) contrib = (50.f / 32.f) * nv * sum;
    }

    __shared__ float partl[4];
    if (lane == 0) partl[wave] = contrib;
    __syncthreads();
    if (threadIdx.x == 0)
        slots[blockIdx.x] = partl[0] + partl[1] + partl[2] + partl[3];
}

// Single-block deterministic sum of 624 slots.
__global__ __launch_bounds__(256)
void yolo_finalize(const float* __restrict__ slots, float* __restrict__ out) {
    __shared__ float red[256];
    int tid = threadIdx.x;
    float v = 0.f;
    for (int i = tid; i < N_SLOTS; i += 256) v += slots[i];
    red[tid] = v;
    __syncthreads();
    for (int off = 128; off > 0; off >>= 1) {
        if (tid < off) red[tid] += red[tid + off];
        __syncthreads();
    }
    if (tid == 0) out[0] = red[0];
}

extern "C" void kernel_launch(void* const* d_in, const int* in_sizes, int n_in,
                              void* d_out, int out_size, void* d_ws, size_t ws_size,
                              hipStream_t stream) {
    const float* p0      = (const float*)d_in[0];
    const float* p1      = (const float*)d_in[1];
    const float* p2      = (const float*)d_in[2];
    const float* targets = (const float*)d_in[3];
    const float* anchors = (const float*)d_in[4];
    float* slots = (float*)d_ws;

    yolo_main<<<N_BLOCKS, 256, 0, stream>>>(p0, p1, p2, targets, anchors, slots);
    yolo_finalize<<<1, 256, 0, stream>>>(slots, (float*)d_out);
}